// Round 1
// baseline (662.809 us; speedup 1.0000x reference)
//
#include <hip/hip_runtime.h>
#include <math.h>

#define PI_F 3.14159265358979323846f

// ---------------- complex helpers ----------------
__device__ __forceinline__ float2 cmul(float2 a, float2 b) {      // a*b
    return make_float2(a.x * b.x - a.y * b.y, a.x * b.y + a.y * b.x);
}
__device__ __forceinline__ float2 cmulc(float2 a, float2 b) {     // a*conj(b)
    return make_float2(a.x * b.x + a.y * b.y, a.y * b.x - a.x * b.y);
}
__device__ __forceinline__ int digitrev4(int p) {                 // reverse 4 base-4 digits of 8-bit p
    return ((p & 3) << 6) | (((p >> 2) & 3) << 4) | (((p >> 4) & 3) << 2) | ((p >> 6) & 3);
}

// ---------------- radix-4 stages (N=256, 4 stages) ----------------
// Forward DIF: stages S=3,2,1,0 (h = 64,16,4,1). Natural in -> base-4 digit-reversed out.
template<int S>
__device__ __forceinline__ void stage_fwd(float2* line, int stride, int j, const float2* lut) {
    const int h = 1 << (2 * S);
    int k  = j & (h - 1);
    int B  = j >> (2 * S);
    int i0 = (B << (2 * S + 2)) + k;
    float2 a0 = line[(i0        ) * stride];
    float2 a1 = line[(i0 +     h) * stride];
    float2 a2 = line[(i0 + 2 * h) * stride];
    float2 a3 = line[(i0 + 3 * h) * stride];
    float2 t0 = make_float2(a0.x + a2.x, a0.y + a2.y);
    float2 t1 = make_float2(a0.x - a2.x, a0.y - a2.y);
    float2 t2 = make_float2(a1.x + a3.x, a1.y + a3.y);
    float2 u  = make_float2(a1.x - a3.x, a1.y - a3.y);
    float2 t3 = make_float2(u.y, -u.x);                 // -i * u
    int eu = k << (6 - 2 * S);                          // W_256 exponent unit (k*64/h)
    line[(i0        ) * stride] = make_float2(t0.x + t2.x, t0.y + t2.y);
    line[(i0 +     h) * stride] = cmul(make_float2(t1.x + t3.x, t1.y + t3.y), lut[eu]);
    line[(i0 + 2 * h) * stride] = cmul(make_float2(t0.x - t2.x, t0.y - t2.y), lut[2 * eu]);
    line[(i0 + 3 * h) * stride] = cmul(make_float2(t1.x - t3.x, t1.y - t3.y), lut[3 * eu]);
}

// Inverse DIT: stages S=0,1,2,3 (h = 1,4,16,64). Digit-reversed in -> natural out. Unnormalized (x N).
template<int S>
__device__ __forceinline__ void stage_inv(float2* line, int stride, int j, const float2* lut) {
    const int h = 1 << (2 * S);
    int k  = j & (h - 1);
    int B  = j >> (2 * S);
    int i0 = (B << (2 * S + 2)) + k;
    int eu = k << (6 - 2 * S);
    float2 b0 = line[(i0        ) * stride];
    float2 b1 = cmulc(line[(i0 +     h) * stride], lut[eu]);
    float2 b2 = cmulc(line[(i0 + 2 * h) * stride], lut[2 * eu]);
    float2 b3 = cmulc(line[(i0 + 3 * h) * stride], lut[3 * eu]);
    float2 t0 = make_float2(b0.x + b2.x, b0.y + b2.y);
    float2 t1 = make_float2(b0.x - b2.x, b0.y - b2.y);
    float2 t2 = make_float2(b1.x + b3.x, b1.y + b3.y);
    float2 u  = make_float2(b1.x - b3.x, b1.y - b3.y);
    float2 t3 = make_float2(-u.y, u.x);                 // +i * u
    line[(i0        ) * stride] = make_float2(t0.x + t2.x, t0.y + t2.y);
    line[(i0 +     h) * stride] = make_float2(t1.x + t3.x, t1.y + t3.y);
    line[(i0 + 2 * h) * stride] = make_float2(t0.x - t2.x, t0.y - t2.y);
    line[(i0 + 3 * h) * stride] = make_float2(t1.x - t3.x, t1.y - t3.y);
}

__device__ __forceinline__ void build_lut(float2* lut, int t) {
    float ang = -2.0f * PI_F * (float)t * (1.0f / 256.0f);
    float sn, cs;
    __sincosf(ang, &sn, &cs);
    lut[t] = make_float2(cs, sn);                       // W_256^t
}

// gain of the (fftshift-space) reference at centered freq (fy, fx)
__device__ __forceinline__ float gain1(float fy, float fx, const float* sw) {
    float r2 = fy * fy + fx * fx;
    float theta = atan2f(fy, fx) + PI_F;                // [0, 2pi]
    int idx = ((int)floorf(theta * (4.0f / PI_F))) & 7; // floor(theta / (pi/4)) mod 8
    float wv = sw[idx];
    return (r2 > 1474.56f) ? wv : 1.0f;                 // r > 0.3*128 <=> r^2 > 1474.56 (r^2 integer)
}

// ---------------- Pass 1: forward FFT along W (rows) ----------------
// Pairs channels (2c, 2c+1) into complex rows; writes re->plane 2c, im->plane 2c+1 of d_out.
__global__ __launch_bounds__(256) void k_fft_rows(const float* __restrict__ x, float* __restrict__ out) {
    __shared__ float2 lut[256];
    __shared__ float2 lds[4][256];
    int t = threadIdx.x;
    build_lut(lut, t);
    __syncthreads();
    int q    = blockIdx.x >> 6;           // image-pair id [0,512)
    int rg   = blockIdx.x & 63;           // row group
    int wv   = t >> 6, lane = t & 63;
    int h    = rg * 4 + wv;
    int plane = ((q >> 7) * 256) + ((q & 127) * 2);
    size_t rowA = ((size_t)plane << 16) + ((size_t)h << 8);
    size_t rowB = rowA + 65536;
    float2* line = lds[wv];
    {
        int w = lane * 4;
        float4 re = *(const float4*)(x + rowA + w);
        float4 im = *(const float4*)(x + rowB + w);
        line[w + 0] = make_float2(re.x, im.x);
        line[w + 1] = make_float2(re.y, im.y);
        line[w + 2] = make_float2(re.z, im.z);
        line[w + 3] = make_float2(re.w, im.w);
    }
    __syncthreads();
    stage_fwd<3>(line, 1, lane, lut); __syncthreads();
    stage_fwd<2>(line, 1, lane, lut); __syncthreads();
    stage_fwd<1>(line, 1, lane, lut); __syncthreads();
    stage_fwd<0>(line, 1, lane, lut); __syncthreads();
    {
        int w = lane * 4;
        float4 re = make_float4(line[w].x, line[w + 1].x, line[w + 2].x, line[w + 3].x);
        float4 im = make_float4(line[w].y, line[w + 1].y, line[w + 2].y, line[w + 3].y);
        *(float4*)(out + rowA + w) = re;
        *(float4*)(out + rowB + w) = im;
    }
}

// ---------------- Pass 2: FFT along H + gain + inverse FFT along H ----------------
// In-place on d_out. Tile = 16 columns x 256 rows in LDS.
__global__ __launch_bounds__(256) void k_fft_cols(float* __restrict__ data, const float* __restrict__ wts) {
    __shared__ float2 lut[256];
    __shared__ float2 tile[256][17];      // [h][c], c<16 used, +1 pad
    __shared__ float  sw[8];
    int t = threadIdx.x;
    build_lut(lut, t);
    if (t < 8) sw[t] = wts[t];
    __syncthreads();
    int q  = blockIdx.x >> 4;             // image-pair id
    int wt = blockIdx.x & 15;             // w-tile
    int w0 = wt * 16;
    int plane = ((q >> 7) * 256) + ((q & 127) * 2);
    size_t baseA = ((size_t)plane << 16) + (size_t)w0;
    size_t baseB = baseA + 65536;
#pragma unroll
    for (int it = 0; it < 4; ++it) {
        int hh = it * 64 + (t >> 2);
        int cc = (t & 3) * 4;
        float4 re = *(const float4*)(data + baseA + hh * 256 + cc);
        float4 im = *(const float4*)(data + baseB + hh * 256 + cc);
        tile[hh][cc + 0] = make_float2(re.x, im.x);
        tile[hh][cc + 1] = make_float2(re.y, im.y);
        tile[hh][cc + 2] = make_float2(re.z, im.z);
        tile[hh][cc + 3] = make_float2(re.w, im.w);
    }
    __syncthreads();
    int c = t & 15, g = t >> 4;
    float2* line = &tile[0][c];           // element i at line[i*17]
    { for (int i2 = 0; i2 < 4; ++i2) stage_fwd<3>(line, 17, g * 4 + i2, lut); } __syncthreads();
    { for (int i2 = 0; i2 < 4; ++i2) stage_fwd<2>(line, 17, g * 4 + i2, lut); } __syncthreads();
    { for (int i2 = 0; i2 < 4; ++i2) stage_fwd<1>(line, 17, g * 4 + i2, lut); } __syncthreads();
    { for (int i2 = 0; i2 < 4; ++i2) stage_fwd<0>(line, 17, g * 4 + i2, lut); } __syncthreads();
    // gain: stored index -> freq via base-4 digit reversal (both dims had radix-4 DIF)
    {
        int kw = digitrev4(w0 + c);
        float fx  = (kw < 128) ? (float)kw : (float)(kw - 256);
        float fx2 = (kw == 128) ? -128.0f : -fx;
#pragma unroll
        for (int it = 0; it < 16; ++it) {
            int hh = it * 16 + g;
            int kh = digitrev4(hh);
            float fy  = (kh < 128) ? (float)kh : (float)(kh - 256);
            float fy2 = (kh == 128) ? -128.0f : -fy;
            float g1 = gain1(fy, fx, sw);
            float g2 = gain1(fy2, fx2, sw);  // G(-k): symmetrize -> real output filter
            float sc = (1.0f + 0.5f * (g1 + g2)) * (1.0f / 65536.0f);  // +identity, /N^2
            float2 v = line[hh * 17];
            line[hh * 17] = make_float2(v.x * sc, v.y * sc);
        }
    }
    __syncthreads();
    { for (int i2 = 0; i2 < 4; ++i2) stage_inv<0>(line, 17, g * 4 + i2, lut); } __syncthreads();
    { for (int i2 = 0; i2 < 4; ++i2) stage_inv<1>(line, 17, g * 4 + i2, lut); } __syncthreads();
    { for (int i2 = 0; i2 < 4; ++i2) stage_inv<2>(line, 17, g * 4 + i2, lut); } __syncthreads();
    { for (int i2 = 0; i2 < 4; ++i2) stage_inv<3>(line, 17, g * 4 + i2, lut); } __syncthreads();
#pragma unroll
    for (int it = 0; it < 4; ++it) {
        int hh = it * 64 + (t >> 2);
        int cc = (t & 3) * 4;
        float4 re = make_float4(tile[hh][cc].x, tile[hh][cc + 1].x, tile[hh][cc + 2].x, tile[hh][cc + 3].x);
        float4 im = make_float4(tile[hh][cc].y, tile[hh][cc + 1].y, tile[hh][cc + 2].y, tile[hh][cc + 3].y);
        *(float4*)(data + baseA + hh * 256 + cc) = re;
        *(float4*)(data + baseB + hh * 256 + cc) = im;
    }
}

// ---------------- Pass 3: inverse FFT along W (rows), in-place on d_out ----------------
__global__ __launch_bounds__(256) void k_ifft_rows(float* __restrict__ data) {
    __shared__ float2 lut[256];
    __shared__ float2 lds[4][256];
    int t = threadIdx.x;
    build_lut(lut, t);
    __syncthreads();
    int q    = blockIdx.x >> 6;
    int rg   = blockIdx.x & 63;
    int wv   = t >> 6, lane = t & 63;
    int h    = rg * 4 + wv;
    int plane = ((q >> 7) * 256) + ((q & 127) * 2);
    size_t rowA = ((size_t)plane << 16) + ((size_t)h << 8);
    size_t rowB = rowA + 65536;
    float2* line = lds[wv];
    {
        int w = lane * 4;
        float4 re = *(const float4*)(data + rowA + w);
        float4 im = *(const float4*)(data + rowB + w);
        line[w + 0] = make_float2(re.x, im.x);
        line[w + 1] = make_float2(re.y, im.y);
        line[w + 2] = make_float2(re.z, im.z);
        line[w + 3] = make_float2(re.w, im.w);
    }
    __syncthreads();
    stage_inv<0>(line, 1, lane, lut); __syncthreads();
    stage_inv<1>(line, 1, lane, lut); __syncthreads();
    stage_inv<2>(line, 1, lane, lut); __syncthreads();
    stage_inv<3>(line, 1, lane, lut); __syncthreads();
    {
        int w = lane * 4;
        float4 re = make_float4(line[w].x, line[w + 1].x, line[w + 2].x, line[w + 3].x);
        float4 im = make_float4(line[w].y, line[w + 1].y, line[w + 2].y, line[w + 3].y);
        *(float4*)(data + rowA + w) = re;  // real part -> channel 2c (final out for even ch)
        *(float4*)(data + rowB + w) = im;  // imag part -> channel 2c+1 (final out for odd ch)
    }
}

extern "C" void kernel_launch(void* const* d_in, const int* in_sizes, int n_in,
                              void* d_out, int out_size, void* d_ws, size_t ws_size,
                              hipStream_t stream) {
    const float* x   = (const float*)d_in[0];
    const float* wts = (const float*)d_in[1];
    float* out = (float*)d_out;
    (void)in_sizes; (void)n_in; (void)d_ws; (void)ws_size; (void)out_size;
    // 512 image-pairs (B=4, C=256 paired), H=W=256
    k_fft_rows <<<512 * 64, 256, 0, stream>>>(x, out);
    k_fft_cols <<<512 * 16, 256, 0, stream>>>(out, wts);
    k_ifft_rows<<<512 * 64, 256, 0, stream>>>(out);
}

// Round 2
// 658.267 us; speedup vs baseline: 1.0069x; 1.0069x over previous
//
#include <hip/hip_runtime.h>
#include <math.h>

#define PI_F 3.14159265358979323846f
// Wave-level LDS sync: DS ops from one wave execute in order; waitcnt drains them,
// "memory" clobber stops compiler reordering. No s_barrier needed for wave-private data.
#define WSYNC() asm volatile("s_waitcnt lgkmcnt(0)" ::: "memory")

// ---------------- complex helpers ----------------
__device__ __forceinline__ float2 cmul(float2 a, float2 b) {      // a*b
    return make_float2(a.x * b.x - a.y * b.y, a.x * b.y + a.y * b.x);
}
__device__ __forceinline__ float2 cmulc(float2 a, float2 b) {     // a*conj(b)
    return make_float2(a.x * b.x + a.y * b.y, a.y * b.x - a.x * b.y);
}
__device__ __forceinline__ int digitrev4(int p) {                 // reverse 4 base-4 digits
    return ((p & 3) << 6) | (((p >> 2) & 3) << 4) | (((p >> 4) & 3) << 2) | ((p >> 6) & 3);
}
// W_256^eu, ^2eu, ^3eu via one sincos + angle addition
__device__ __forceinline__ void tw3(int eu, float2& w1, float2& w2, float2& w3) {
    float sn, cs;
    __sincosf(-(2.0f * PI_F / 256.0f) * (float)eu, &sn, &cs);
    w1 = make_float2(cs, sn);
    w2 = cmul(w1, w1);
    w3 = cmul(w2, w1);
}

// ---------------- radix-4 butterflies (N=256, stride-1 line) ----------------
// Forward DIF stage S (h=4^S): natural in -> base-4 digit-reversed out over stages 3,2,1,0.
template<int S>
__device__ __forceinline__ void stage_fwd_j(float2* line, int j, float2 w1, float2 w2, float2 w3) {
    const int h = 1 << (2 * S);
    int k  = j & (h - 1);
    int i0 = ((j >> (2 * S)) << (2 * S + 2)) + k;
    float2 a0 = line[i0], a1 = line[i0 + h], a2 = line[i0 + 2 * h], a3 = line[i0 + 3 * h];
    float2 t0 = make_float2(a0.x + a2.x, a0.y + a2.y);
    float2 t1 = make_float2(a0.x - a2.x, a0.y - a2.y);
    float2 t2 = make_float2(a1.x + a3.x, a1.y + a3.y);
    float2 u  = make_float2(a1.x - a3.x, a1.y - a3.y);
    float2 t3 = make_float2(u.y, -u.x);                 // -i*u
    line[i0]         = make_float2(t0.x + t2.x, t0.y + t2.y);
    line[i0 + h]     = cmul(make_float2(t1.x + t3.x, t1.y + t3.y), w1);
    line[i0 + 2 * h] = cmul(make_float2(t0.x - t2.x, t0.y - t2.y), w2);
    line[i0 + 3 * h] = cmul(make_float2(t1.x - t3.x, t1.y - t3.y), w3);
}
// Inverse DIT stage S: digit-reversed in -> natural out over stages 0,1,2,3. Unnormalized.
template<int S>
__device__ __forceinline__ void stage_inv_j(float2* line, int j, float2 w1, float2 w2, float2 w3) {
    const int h = 1 << (2 * S);
    int k  = j & (h - 1);
    int i0 = ((j >> (2 * S)) << (2 * S + 2)) + k;
    float2 b0 = line[i0];
    float2 b1 = cmulc(line[i0 + h], w1);
    float2 b2 = cmulc(line[i0 + 2 * h], w2);
    float2 b3 = cmulc(line[i0 + 3 * h], w3);
    float2 t0 = make_float2(b0.x + b2.x, b0.y + b2.y);
    float2 t1 = make_float2(b0.x - b2.x, b0.y - b2.y);
    float2 t2 = make_float2(b1.x + b3.x, b1.y + b3.y);
    float2 u  = make_float2(b1.x - b3.x, b1.y - b3.y);
    float2 t3 = make_float2(-u.y, u.x);                 // +i*u
    line[i0]         = make_float2(t0.x + t2.x, t0.y + t2.y);
    line[i0 + h]     = make_float2(t1.x + t3.x, t1.y + t3.y);
    line[i0 + 2 * h] = make_float2(t0.x - t2.x, t0.y - t2.y);
    line[i0 + 3 * h] = make_float2(t1.x - t3.x, t1.y - t3.y);
}

// gain of the (fftshift-space) reference at centered freq (fy, fx)
__device__ __forceinline__ float gain1(float fy, float fx, const float* sw) {
    float r2 = fy * fy + fx * fx;
    float theta = atan2f(fy, fx) + PI_F;
    int idx = ((int)floorf(theta * (4.0f / PI_F))) & 7;
    float wv = sw[idx];
    return (r2 > 1474.56f) ? wv : 1.0f;                 // r > 0.3*128, r^2 integer
}

// ---------------- gain LUT setup: sc[w_stored][h_stored] (digit-reversed coords) ----------------
__global__ __launch_bounds__(256) void k_gain_lut(const float* __restrict__ wts, float* __restrict__ lut2) {
    __shared__ float sw[8];
    int h = threadIdx.x, w = blockIdx.x;
    if (h < 8) sw[h] = wts[h];
    __syncthreads();
    int kw = digitrev4(w), kh = digitrev4(h);
    float fx  = (kw < 128) ? (float)kw : (float)(kw - 256);
    float fx2 = (kw == 128) ? -128.0f : -fx;
    float fy  = (kh < 128) ? (float)kh : (float)(kh - 256);
    float fy2 = (kh == 128) ? -128.0f : -fy;
    float g1 = gain1(fy, fx, sw);
    float g2 = gain1(fy2, fx2, sw);                     // symmetrize -> real filter
    lut2[w * 256 + h] = (1.0f + 0.5f * (g1 + g2)) * (1.0f / 65536.0f);
}

// ---------------- Pass 1: forward FFT along W. Each wave owns 2 rows; no block barriers. ----------------
__global__ __launch_bounds__(256) void k_row_fwd(const float* __restrict__ x, float* __restrict__ out) {
    __shared__ float2 lds[8][256];
    int t = threadIdx.x, wv = t >> 6, lane = t & 63;
    int gr = blockIdx.x * 8 + wv * 2;                   // global row id (pair-aligned, same image)
    int q = gr >> 8, h = gr & 255;
    int plane = ((q >> 7) << 8) + ((q & 127) << 1);
    size_t rA = ((size_t)plane << 16) + ((size_t)h << 8);
    size_t rB = rA + 65536;
    float2* L0 = lds[wv * 2];
    float2* L1 = lds[wv * 2 + 1];
    int w = lane * 4;
    float4 re0 = *(const float4*)(x + rA + w);
    float4 im0 = *(const float4*)(x + rB + w);
    float4 re1 = *(const float4*)(x + rA + 256 + w);
    float4 im1 = *(const float4*)(x + rB + 256 + w);
    *(float4*)&L0[w]     = make_float4(re0.x, im0.x, re0.y, im0.y);
    *(float4*)&L0[w + 2] = make_float4(re0.z, im0.z, re0.w, im0.w);
    *(float4*)&L1[w]     = make_float4(re1.x, im1.x, re1.y, im1.y);
    *(float4*)&L1[w + 2] = make_float4(re1.z, im1.z, re1.w, im1.w);
    WSYNC();
    { float2 w1,w2,w3; tw3((lane & 63) << 0, w1,w2,w3);
      stage_fwd_j<3>(L0, lane, w1,w2,w3); stage_fwd_j<3>(L1, lane, w1,w2,w3); WSYNC(); }
    { float2 w1,w2,w3; tw3((lane & 15) << 2, w1,w2,w3);
      stage_fwd_j<2>(L0, lane, w1,w2,w3); stage_fwd_j<2>(L1, lane, w1,w2,w3); WSYNC(); }
    { float2 w1,w2,w3; tw3((lane & 3) << 4, w1,w2,w3);
      stage_fwd_j<1>(L0, lane, w1,w2,w3); stage_fwd_j<1>(L1, lane, w1,w2,w3); WSYNC(); }
    { float2 one = make_float2(1.0f, 0.0f);
      stage_fwd_j<0>(L0, lane, one,one,one); stage_fwd_j<0>(L1, lane, one,one,one); WSYNC(); }
    float4 a0 = *(float4*)&L0[w], a1 = *(float4*)&L0[w + 2];
    float4 b0 = *(float4*)&L1[w], b1 = *(float4*)&L1[w + 2];
    *(float4*)(out + rA + w)       = make_float4(a0.x, a0.z, a1.x, a1.z);
    *(float4*)(out + rB + w)       = make_float4(a0.y, a0.w, a1.y, a1.w);
    *(float4*)(out + rA + 256 + w) = make_float4(b0.x, b0.z, b1.x, b1.z);
    *(float4*)(out + rB + 256 + w) = make_float4(b0.y, b0.w, b1.y, b1.w);
}

// ---------------- Pass 2: col FFT + gain + col IFFT. Wave owns 4 columns; 2 block barriers. ----------------
template<int S>
__device__ __forceinline__ void col_stage_fwd(float2* line, int jb) {
#pragma unroll
    for (int i2 = 0; i2 < 4; ++i2) {
        int j = jb + 16 * i2;
        int k = j & ((1 << (2 * S)) - 1);
        float2 w1,w2,w3; tw3(k << (6 - 2 * S), w1,w2,w3);
        stage_fwd_j<S>(line, j, w1,w2,w3);
    }
}
template<int S>
__device__ __forceinline__ void col_stage_inv(float2* line, int jb) {
#pragma unroll
    for (int i2 = 0; i2 < 4; ++i2) {
        int j = jb + 16 * i2;
        int k = j & ((1 << (2 * S)) - 1);
        float2 w1,w2,w3; tw3(k << (6 - 2 * S), w1,w2,w3);
        stage_inv_j<S>(line, j, w1,w2,w3);
    }
}

template<bool USE_LUT>
__global__ __launch_bounds__(256) void k_col(float* __restrict__ data,
                                            const float* __restrict__ lut2,
                                            const float* __restrict__ wts) {
    __shared__ float2 tile[16][258];                    // [col][h], pad 2
    __shared__ float sw[8];
    int t = threadIdx.x;
    if (!USE_LUT && t < 8) sw[t] = wts[t];
    int q = blockIdx.x >> 4, wt = blockIdx.x & 15, w0 = wt * 16;
    int plane = ((q >> 7) << 8) + ((q & 127) << 1);
    size_t baseA = ((size_t)plane << 16) + (size_t)w0;
    size_t baseB = baseA + 65536;
    // -------- staging in: thread -> cols c0..c0+3, rows h0..h0+3 --------
    int c0 = (t & 3) * 4, h0 = (t >> 2) * 4;
    {
        float4 reR[4], imR[4];
#pragma unroll
        for (int r = 0; r < 4; ++r) {
            reR[r] = *(const float4*)(data + baseA + (size_t)(h0 + r) * 256 + c0);
            imR[r] = *(const float4*)(data + baseB + (size_t)(h0 + r) * 256 + c0);
        }
#pragma unroll
        for (int k = 0; k < 4; ++k) {
            float r0 = (&reR[0].x)[k], i0v = (&imR[0].x)[k];
            float r1 = (&reR[1].x)[k], i1v = (&imR[1].x)[k];
            float r2 = (&reR[2].x)[k], i2v = (&imR[2].x)[k];
            float r3 = (&reR[3].x)[k], i3v = (&imR[3].x)[k];
            *(float4*)&tile[c0 + k][h0]     = make_float4(r0, i0v, r1, i1v);
            *(float4*)&tile[c0 + k][h0 + 2] = make_float4(r2, i2v, r3, i3v);
        }
    }
    __syncthreads();
    // -------- wave-private column FFTs --------
    int wv = t >> 6, lane = t & 63;
    int col = wv * 4 + (lane & 3);
    int jb  = lane >> 2;                                // 0..15
    float2* line = tile[col];
    col_stage_fwd<3>(line, jb); WSYNC();
    col_stage_fwd<2>(line, jb); WSYNC();
    col_stage_fwd<1>(line, jb); WSYNC();
    col_stage_fwd<0>(line, jb); WSYNC();
    // -------- gain (digit-reversed coords both dims) --------
    {
        int hb = jb * 16;
        if (USE_LUT) {
            const float* lp = lut2 + (size_t)(w0 + col) * 256 + hb;
#pragma unroll
            for (int ch = 0; ch < 4; ++ch) {
                float4 s4 = *(const float4*)(lp + ch * 4);
#pragma unroll
                for (int e = 0; e < 4; ++e) {
                    int hh = hb + ch * 4 + e;
                    float sc = (&s4.x)[e];
                    float2 v = line[hh];
                    line[hh] = make_float2(v.x * sc, v.y * sc);
                }
            }
        } else {
            int kw = digitrev4(w0 + col);
            float fx  = (kw < 128) ? (float)kw : (float)(kw - 256);
            float fx2 = (kw == 128) ? -128.0f : -fx;
#pragma unroll
            for (int m = 0; m < 16; ++m) {
                int hh = hb + m;
                int kh = digitrev4(hh);
                float fy  = (kh < 128) ? (float)kh : (float)(kh - 256);
                float fy2 = (kh == 128) ? -128.0f : -fy;
                float g1 = gain1(fy, fx, sw);
                float g2 = gain1(fy2, fx2, sw);
                float sc = (1.0f + 0.5f * (g1 + g2)) * (1.0f / 65536.0f);
                float2 v = line[hh];
                line[hh] = make_float2(v.x * sc, v.y * sc);
            }
        }
        WSYNC();
    }
    col_stage_inv<0>(line, jb); WSYNC();
    col_stage_inv<1>(line, jb); WSYNC();
    col_stage_inv<2>(line, jb); WSYNC();
    col_stage_inv<3>(line, jb); WSYNC();
    __syncthreads();
    // -------- staging out (mirror of staging in) --------
    {
        float2 v[4][4];                                 // [col k][row r]
#pragma unroll
        for (int k = 0; k < 4; ++k) {
            float4 lo = *(float4*)&tile[c0 + k][h0];
            float4 hi = *(float4*)&tile[c0 + k][h0 + 2];
            v[k][0] = make_float2(lo.x, lo.y);
            v[k][1] = make_float2(lo.z, lo.w);
            v[k][2] = make_float2(hi.x, hi.y);
            v[k][3] = make_float2(hi.z, hi.w);
        }
#pragma unroll
        for (int r = 0; r < 4; ++r) {
            *(float4*)(data + baseA + (size_t)(h0 + r) * 256 + c0) =
                make_float4(v[0][r].x, v[1][r].x, v[2][r].x, v[3][r].x);
            *(float4*)(data + baseB + (size_t)(h0 + r) * 256 + c0) =
                make_float4(v[0][r].y, v[1][r].y, v[2][r].y, v[3][r].y);
        }
    }
}

// ---------------- Pass 3: inverse FFT along W. Each wave owns 2 rows; no block barriers. ----------------
__global__ __launch_bounds__(256) void k_row_inv(float* __restrict__ data) {
    __shared__ float2 lds[8][256];
    int t = threadIdx.x, wv = t >> 6, lane = t & 63;
    int gr = blockIdx.x * 8 + wv * 2;
    int q = gr >> 8, h = gr & 255;
    int plane = ((q >> 7) << 8) + ((q & 127) << 1);
    size_t rA = ((size_t)plane << 16) + ((size_t)h << 8);
    size_t rB = rA + 65536;
    float2* L0 = lds[wv * 2];
    float2* L1 = lds[wv * 2 + 1];
    int w = lane * 4;
    float4 re0 = *(const float4*)(data + rA + w);
    float4 im0 = *(const float4*)(data + rB + w);
    float4 re1 = *(const float4*)(data + rA + 256 + w);
    float4 im1 = *(const float4*)(data + rB + 256 + w);
    *(float4*)&L0[w]     = make_float4(re0.x, im0.x, re0.y, im0.y);
    *(float4*)&L0[w + 2] = make_float4(re0.z, im0.z, re0.w, im0.w);
    *(float4*)&L1[w]     = make_float4(re1.x, im1.x, re1.y, im1.y);
    *(float4*)&L1[w + 2] = make_float4(re1.z, im1.z, re1.w, im1.w);
    WSYNC();
    { float2 one = make_float2(1.0f, 0.0f);
      stage_inv_j<0>(L0, lane, one,one,one); stage_inv_j<0>(L1, lane, one,one,one); WSYNC(); }
    { float2 w1,w2,w3; tw3((lane & 3) << 4, w1,w2,w3);
      stage_inv_j<1>(L0, lane, w1,w2,w3); stage_inv_j<1>(L1, lane, w1,w2,w3); WSYNC(); }
    { float2 w1,w2,w3; tw3((lane & 15) << 2, w1,w2,w3);
      stage_inv_j<2>(L0, lane, w1,w2,w3); stage_inv_j<2>(L1, lane, w1,w2,w3); WSYNC(); }
    { float2 w1,w2,w3; tw3((lane & 63) << 0, w1,w2,w3);
      stage_inv_j<3>(L0, lane, w1,w2,w3); stage_inv_j<3>(L1, lane, w1,w2,w3); WSYNC(); }
    float4 a0 = *(float4*)&L0[w], a1 = *(float4*)&L0[w + 2];
    float4 b0 = *(float4*)&L1[w], b1 = *(float4*)&L1[w + 2];
    *(float4*)(data + rA + w)       = make_float4(a0.x, a0.z, a1.x, a1.z);   // re -> ch 2c
    *(float4*)(data + rB + w)       = make_float4(a0.y, a0.w, a1.y, a1.w);   // im -> ch 2c+1
    *(float4*)(data + rA + 256 + w) = make_float4(b0.x, b0.z, b1.x, b1.z);
    *(float4*)(data + rB + 256 + w) = make_float4(b0.y, b0.w, b1.y, b1.w);
}

extern "C" void kernel_launch(void* const* d_in, const int* in_sizes, int n_in,
                              void* d_out, int out_size, void* d_ws, size_t ws_size,
                              hipStream_t stream) {
    const float* x   = (const float*)d_in[0];
    const float* wts = (const float*)d_in[1];
    float* out = (float*)d_out;
    (void)in_sizes; (void)n_in; (void)out_size;
    bool use_lut = (ws_size >= 256 * 256 * sizeof(float)) && (d_ws != nullptr);
    if (use_lut) {
        k_gain_lut<<<256, 256, 0, stream>>>(wts, (float*)d_ws);
    }
    // 512 image-pairs (B=4, C=256 paired), H=W=256; 131072 rows total, 8 per block
    k_row_fwd<<<16384, 256, 0, stream>>>(x, out);
    if (use_lut) {
        k_col<true><<<8192, 256, 0, stream>>>(out, (const float*)d_ws, wts);
    } else {
        k_col<false><<<8192, 256, 0, stream>>>(out, nullptr, wts);
    }
    k_row_inv<<<16384, 256, 0, stream>>>(out);
}